// Round 6
// baseline (141.573 us; speedup 1.0000x reference)
//
#include <hip/hip_runtime.h>
#include <hip/hip_bf16.h>

#define NB 8192   // batch
#define ND 512    // feature dim
#define NC 512    // num classes
#define MARGIN_F 1.0f
#define BIGF 3.0e38f
#define LSTR 40   // LDS row stride in shorts (BK=32 + 8 pad) -> 2-way max on b128

typedef __attribute__((ext_vector_type(8))) short          bf16x8;
typedef __attribute__((ext_vector_type(8))) unsigned short ushort8;
typedef __attribute__((ext_vector_type(4))) float          f32x4;

__device__ __forceinline__ unsigned fkey(float f) {
    unsigned u = __float_as_uint(f);
    unsigned mask = (u & 0x80000000u) ? 0xFFFFFFFFu : 0x80000000u;
    return u ^ mask;
}
__device__ __forceinline__ float finv(unsigned k) {
    unsigned mask = (k & 0x80000000u) ? 0x80000000u : 0xFFFFFFFFu;
    return __uint_as_float(k ^ mask);
}
__device__ __forceinline__ unsigned short f2bf(float f) {
    __hip_bfloat16 h = __float2bfloat16(f);
    return __builtin_bit_cast(unsigned short, h);
}

// -------------------------------------------------------------------------
// prep: negmin init (all 64 blocks), histogram + done init (block 0 only).
// Touches only ~70 KB of ws -> minimal dirty-LLC coupling.
// -------------------------------------------------------------------------
__global__ __launch_bounds__(256) void k_prep(
    const int* __restrict__ targets, unsigned* __restrict__ counts,
    unsigned* __restrict__ negmin, unsigned* __restrict__ done)
{
    const int bid = blockIdx.x, tid = threadIdx.x;
    if (tid < 128) negmin[bid * 128 + tid] = 0xFFFFFFFFu;
    if (bid != 0) return;
    __shared__ unsigned hist[NC];
    for (int i = tid; i < NC; i += 256) hist[i] = 0u;
    __syncthreads();
    for (int i = tid; i < NB; i += 256) atomicAdd(&hist[targets[i]], 1u);
    __syncthreads();
    for (int i = tid; i < NC; i += 256) counts[i] = hist[i];
    if (tid == 0) *done = 0u;
}

// -------------------------------------------------------------------------
// k2: everything else. Reads fp32 inputs/centers DIRECTLY (no ws round-trip),
// converts to bf16 in-register, manual padded LDS staging, bf16 MFMA,
// csq/rsq computed on the fly, masked-min epilogue, last-block finalize.
// BM=128, BN=64, BK=32, 256 threads = 4 waves (2 row-halves x 2 col-halves).
// grid = 512 blocks (rtile = bid&63: all 8 ctile-blocks of a rtile land on
// one XCD since 64 % 8 == 0 -> A rows L2-resident), 2 blocks/CU.
// -------------------------------------------------------------------------
__global__ __launch_bounds__(256) void k2_mfma(
    const float* __restrict__ inputs, const float* __restrict__ centers,
    const int* __restrict__ targets, const unsigned* __restrict__ counts,
    unsigned* __restrict__ negmin, float* __restrict__ apval,
    float* __restrict__ rsq, unsigned* __restrict__ done,
    float* __restrict__ out)
{
    __shared__ __align__(16) unsigned short As[128 * LSTR];  // 10.2 KB
    __shared__ __align__(16) unsigned short Bs[64 * LSTR];   // 5.1 KB
    __shared__ int      tgtL[128];
    __shared__ float    csqL[64];
    __shared__ unsigned cntL[64];
    __shared__ unsigned ldsmin[128];
    __shared__ float    red[8];
    __shared__ int      lastFlag;

    const int tid  = threadIdx.x;
    const int w    = tid >> 6;
    const int lane = tid & 63;
    const int wm   = w >> 1;      // 0..1 : 64-row half
    const int wn   = w & 1;       // 0..1 : 32-col half
    const int qd   = lane >> 4;   // quad 0..3
    const int ln   = lane & 15;

    const int bid   = blockIdx.x;
    const int rbase = (bid & 63) * 128;
    const int cbase = (bid >> 6) * 64;

    if (tid < 128) { tgtL[tid] = targets[rbase + tid]; ldsmin[tid] = 0xFFFFFFFFu; }
    if (tid < 64)  cntL[tid] = counts[cbase + tid];

    // staging map: A: thread t -> row t>>1, k-half (t&1)*16 (16 floats/iter).
    //              B: thread t -> row t>>2, k-quarter (t&3)*8 (8 floats/iter).
    const int arow = tid >> 1, apart = tid & 1;
    const int brow = tid >> 2, bpart = tid & 3;
    const float* gA = inputs  + (size_t)(rbase + arow) * ND + apart * 16;
    const float* gB = centers + (size_t)(cbase + brow) * ND + bpart * 8;
    unsigned short* lA = &As[arow * LSTR + apart * 16];
    unsigned short* lB = &Bs[brow * LSTR + bpart * 8];

    const bool do_rsq = (cbase == 0);

    float4 bufA[2][4];
    float4 bufB[2][2];
    #pragma unroll
    for (int q = 0; q < 4; ++q) bufA[0][q] = *(const float4*)(gA + q * 4);
    bufB[0][0] = *(const float4*)(gB + 0);
    bufB[0][1] = *(const float4*)(gB + 4);

    f32x4 acc[4][2] = {};   // 4 row-frags x 2 col-frags of 16x16
    float rs = 0.0f;        // row sqnorm partial (ctile 0 only)
    float bq = 0.0f;        // center sqnorm partial

    #pragma unroll
    for (int kbi = 0; kbi < 16; ++kbi) {
        const int cu = kbi & 1, nx = cu ^ 1;
        if (kbi < 15) {   // prefetch next K-slice while we convert/stage this one
            const int kn = (kbi + 1) * 32;
            #pragma unroll
            for (int q = 0; q < 4; ++q) bufA[nx][q] = *(const float4*)(gA + kn + q * 4);
            bufB[nx][0] = *(const float4*)(gB + kn + 0);
            bufB[nx][1] = *(const float4*)(gB + kn + 4);
        }

        ushort8 a0, a1, b0;
        {
            float4 u = bufA[cu][0], v = bufA[cu][1];
            a0[0]=f2bf(u.x); a0[1]=f2bf(u.y); a0[2]=f2bf(u.z); a0[3]=f2bf(u.w);
            a0[4]=f2bf(v.x); a0[5]=f2bf(v.y); a0[6]=f2bf(v.z); a0[7]=f2bf(v.w);
            if (do_rsq) rs += u.x*u.x+u.y*u.y+u.z*u.z+u.w*u.w
                            + v.x*v.x+v.y*v.y+v.z*v.z+v.w*v.w;
            u = bufA[cu][2]; v = bufA[cu][3];
            a1[0]=f2bf(u.x); a1[1]=f2bf(u.y); a1[2]=f2bf(u.z); a1[3]=f2bf(u.w);
            a1[4]=f2bf(v.x); a1[5]=f2bf(v.y); a1[6]=f2bf(v.z); a1[7]=f2bf(v.w);
            if (do_rsq) rs += u.x*u.x+u.y*u.y+u.z*u.z+u.w*u.w
                            + v.x*v.x+v.y*v.y+v.z*v.z+v.w*v.w;
        }
        {
            float4 u = bufB[cu][0], v = bufB[cu][1];
            b0[0]=f2bf(u.x); b0[1]=f2bf(u.y); b0[2]=f2bf(u.z); b0[3]=f2bf(u.w);
            b0[4]=f2bf(v.x); b0[5]=f2bf(v.y); b0[6]=f2bf(v.z); b0[7]=f2bf(v.w);
            bq += u.x*u.x+u.y*u.y+u.z*u.z+u.w*u.w
                + v.x*v.x+v.y*v.y+v.z*v.z+v.w*v.w;
        }

        __syncthreads();                 // prev iter's frag reads done
        *(ushort8*)lA       = a0;
        *(ushort8*)(lA + 8) = a1;
        *(ushort8*)lB       = b0;
        __syncthreads();                 // tile visible

        bf16x8 a[4], b[2];
        #pragma unroll
        for (int i = 0; i < 4; ++i)
            a[i] = *(const bf16x8*)&As[(wm * 64 + i * 16 + ln) * LSTR + qd * 8];
        #pragma unroll
        for (int j = 0; j < 2; ++j)
            b[j] = *(const bf16x8*)&Bs[(wn * 32 + j * 16 + ln) * LSTR + qd * 8];
        #pragma unroll
        for (int i = 0; i < 4; ++i)
            #pragma unroll
            for (int j = 0; j < 2; ++j)
                acc[i][j] = __builtin_amdgcn_mfma_f32_16x16x32_bf16(a[i], b[j], acc[i][j], 0, 0, 0);
    }

    // row sqnorms (ctile 0 only): threads 2r, 2r+1 hold halves of row r
    if (do_rsq) {
        float r2 = rs + __shfl_xor(rs, 1);
        if (apart == 0) rsq[rbase + arow] = r2;
    }
    // center sqnorms: threads 4r..4r+3 hold quarters of center row r
    {
        float b2 = bq;
        b2 += __shfl_xor(b2, 1);
        b2 += __shfl_xor(b2, 2);
        if (bpart == 0) csqL[brow] = b2;
    }
    __syncthreads();   // csqL visible

    // Epilogue. C/D layout: col = lane&15, row = (lane>>4)*4 + reg.
    #pragma unroll
    for (int i = 0; i < 4; ++i) {
        #pragma unroll
        for (int r = 0; r < 4; ++r) {
            const int rlocal = wm * 64 + i * 16 + qd * 4 + r;
            const int grow   = rbase + rlocal;
            const int tr     = tgtL[rlocal];
            float m = BIGF;
            #pragma unroll
            for (int j = 0; j < 2; ++j) {
                const int clocal = wn * 32 + j * 16 + ln;
                const float val = csqL[clocal] - 2.0f * acc[i][j][r];
                if (cbase + clocal == tr) {
                    apval[grow] = val;                 // exactly one writer per row
                } else if (cntL[clocal] > 0u) {
                    m = fminf(m, val);
                }
            }
            #pragma unroll
            for (int off = 1; off < 16; off <<= 1)
                m = fminf(m, __shfl_xor(m, off));
            if (ln == 0) atomicMin(&ldsmin[rlocal], fkey(m));
        }
    }
    __syncthreads();
    if (tid < 128) {
        unsigned v = ldsmin[tid];
        if (v != 0xFFFFFFFFu) atomicMin(&negmin[rbase + tid], v);
    }

    // ---- last-done block runs the finalize ----
    __threadfence();
    if (tid == 0) {
        unsigned old = atomicAdd(done, 1u);
        lastFlag = (old == 511u) ? 1 : 0;
    }
    __syncthreads();
    if (!lastFlag) return;
    __threadfence();

    float la = 0.0f, lp = 0.0f;
    for (int rr = tid; rr < NB; rr += 256) {
        float s  = rsq[rr];
        float an = sqrtf(fmaxf(s + finv(negmin[rr]), 1e-12f));
        float ap = sqrtf(fmaxf(s + apval[rr],        1e-12f));
        la += fmaxf(0.0f, ap - an + MARGIN_F);
        lp += (an > ap) ? 1.0f : 0.0f;
    }
    #pragma unroll
    for (int off = 32; off > 0; off >>= 1) {
        la += __shfl_down(la, off);
        lp += __shfl_down(lp, off);
    }
    if (lane == 0) { red[w] = la; red[4 + w] = lp; }
    __syncthreads();
    if (tid == 0) {
        float A = 0.0f, P = 0.0f;
        #pragma unroll
        for (int i = 0; i < 4; ++i) { A += red[i]; P += red[4 + i]; }
        out[0] = A / (float)NB;
        out[1] = P / (float)NB;
    }
}

extern "C" void kernel_launch(void* const* d_in, const int* in_sizes, int n_in,
                              void* d_out, int out_size, void* d_ws, size_t ws_size,
                              hipStream_t stream) {
    const float* inputs  = (const float*)d_in[0];
    const int*   targets = (const int*)d_in[1];
    const float* centers = (const float*)d_in[2];
    float* out = (float*)d_out;

    // ws layout (bytes) — total footprint ~100 KB (minimize dirty-LLC coupling):
    char* wp = (char*)d_ws;
    unsigned* negmin = (unsigned*)(wp);            // 8192*4 = 32768
    float*    apval  = (float*)(wp + 32768);       // 8192*4
    float*    rsq    = (float*)(wp + 65536);       // 8192*4
    unsigned* counts = (unsigned*)(wp + 98304);    // 512*4
    unsigned* done   = (unsigned*)(wp + 100352);   // 4

    k_prep<<<64, 256, 0, stream>>>(targets, counts, negmin, done);
    k2_mfma<<<512, 256, 0, stream>>>(inputs, centers, targets, counts,
                                     negmin, apval, rsq, done, out);
}

// Round 7
// 94.354 us; speedup vs baseline: 1.5004x; 1.5004x over previous
//
#include <hip/hip_runtime.h>
#include <hip/hip_bf16.h>

#define NB 8192   // batch
#define ND 512    // feature dim
#define NC 512    // num classes
#define MARGIN_F 1.0f
#define BIGF 3.0e38f

typedef __attribute__((ext_vector_type(8))) short bf16x8;
typedef __attribute__((ext_vector_type(4))) float f32x4;

__device__ __forceinline__ unsigned fkey(float f) {
    unsigned u = __float_as_uint(f);
    unsigned mask = (u & 0x80000000u) ? 0xFFFFFFFFu : 0x80000000u;
    return u ^ mask;
}
__device__ __forceinline__ float finv(unsigned k) {
    unsigned mask = (k & 0x80000000u) ? 0x80000000u : 0xFFFFFFFFu;
    return __uint_as_float(k ^ mask);
}
__device__ __forceinline__ unsigned short f2bf(float f) {
    __hip_bfloat16 h = __float2bfloat16(f);
    return __builtin_bit_cast(unsigned short, h);
}

#define GLOAD_LDS16(g, l)                                                    \
    __builtin_amdgcn_global_load_lds(                                        \
        (const __attribute__((address_space(1))) void*)(g),                  \
        (__attribute__((address_space(3))) void*)(l), 16, 0, 0)

// -------------------------------------------------------------------------
// k0: fp32->bf16 convert (inputs + centers), row/center sqnorms, negmin
//     init, class histogram. grid = 2177 x 256. (R2-proven structure.)
// -------------------------------------------------------------------------
__global__ __launch_bounds__(256) void k0_prep(
    const float* __restrict__ inputs, const int* __restrict__ targets,
    const float* __restrict__ centers,
    unsigned short* __restrict__ inB, unsigned short* __restrict__ cenB,
    float* __restrict__ rsq, float* __restrict__ csq,
    unsigned* __restrict__ counts, unsigned* __restrict__ negmin)
{
    const int bid = blockIdx.x;
    const int tid = threadIdx.x;

    if (bid == 2176) {   // histogram block
        __shared__ unsigned hist[NC];
        for (int i = tid; i < NC; i += 256) hist[i] = 0u;
        __syncthreads();
        for (int i = tid; i < NB; i += 256) atomicAdd(&hist[targets[i]], 1u);
        __syncthreads();
        for (int i = tid; i < NC; i += 256) counts[i] = hist[i];
        return;
    }

    const int wave = tid >> 6, lane = tid & 63;
    const float* src;
    unsigned short* dst;
    float* sqdst;
    int row;
    bool is_input = (bid < 2048);
    if (is_input) {
        row   = bid * 4 + wave;
        src   = inputs + (size_t)row * ND;
        dst   = inB + (size_t)row * ND;
        sqdst = rsq + row;
    } else {
        row   = (bid - 2048) * 4 + wave;
        src   = centers + (size_t)row * ND;
        dst   = cenB + (size_t)row * ND;
        sqdst = csq + row;
    }

    float4 v1 = ((const float4*)src)[lane];
    float4 v2 = ((const float4*)src)[lane + 64];
    float s = v1.x*v1.x + v1.y*v1.y + v1.z*v1.z + v1.w*v1.w
            + v2.x*v2.x + v2.y*v2.y + v2.z*v2.z + v2.w*v2.w;

    ushort4 o1, o2;
    o1.x = f2bf(v1.x); o1.y = f2bf(v1.y); o1.z = f2bf(v1.z); o1.w = f2bf(v1.w);
    o2.x = f2bf(v2.x); o2.y = f2bf(v2.y); o2.z = f2bf(v2.z); o2.w = f2bf(v2.w);
    ((ushort4*)dst)[lane]      = o1;
    ((ushort4*)dst)[lane + 64] = o2;

    #pragma unroll
    for (int off = 32; off > 0; off >>= 1) s += __shfl_down(s, off);
    if (lane == 0) {
        *sqdst = s;
        if (is_input) negmin[row] = 0xFFFFFFFFu;
    }
}

// -------------------------------------------------------------------------
// k2: bf16 MFMA GEMM + masked-min epilogue. NO device fences, NO finalize
// (that's the A/B variable vs R5). BM=128, BN=64, BK=32, 256 threads =
// 4 waves (2 row-halves x 2 col-halves, wave tile 64x32).
// grid = 512 blocks (rtile = bid&63 -> XCD-local A reuse), 2 blocks/CU so
// the two co-resident blocks hide each other's barrier drains.
// -------------------------------------------------------------------------
__global__ __launch_bounds__(256) void k2_mfma(
    const unsigned short* __restrict__ Ain, const unsigned short* __restrict__ cenB,
    const int* __restrict__ targets, const unsigned* __restrict__ counts,
    const float* __restrict__ csq,
    unsigned* __restrict__ negmin, float* __restrict__ apval)
{
    __shared__ __align__(16) unsigned short As[128 * 32];  // no pad: global_load_lds layout
    __shared__ __align__(16) unsigned short Bs[64 * 32];
    __shared__ int      tgtL[128];
    __shared__ float    csqL[64];
    __shared__ unsigned ldsmin[128];

    const int tid  = threadIdx.x;
    const int w    = tid >> 6;
    const int lane = tid & 63;
    const int wm   = w >> 1;      // 0..1 : 64-row half
    const int wn   = w & 1;       // 0..1 : 32-col half
    const int qd   = lane >> 4;   // quad 0..3
    const int ln   = lane & 15;

    const int bid   = blockIdx.x;
    const int rbase = (bid & 63) * 128;
    const int cbase = (bid >> 6) * 64;

    if (tid < 128) { tgtL[tid] = targets[rbase + tid]; ldsmin[tid] = 0xFFFFFFFFu; }
    if (tid < 64) {
        const int c = cbase + tid;
        csqL[tid] = (counts[c] > 0u) ? csq[c] : BIGF;   // empty class never wins min
    }

    // Staging map (wave-uniform LDS base + lane*16B, m97 pattern):
    // A: wave w stages rows [w*32, w*32+32) in two 16-row chunks.
    // B: wave w stages rows [w*16, w*16+16).
    const int arow0 = w * 32 + (lane >> 2);
    const int brow  = w * 16 + (lane >> 2);
    const int scol  = (lane & 3) * 8;
    const unsigned short* gA0 = Ain  + (size_t)(rbase + arow0)      * ND + scol;
    const unsigned short* gA1 = Ain  + (size_t)(rbase + arow0 + 16) * ND + scol;
    const unsigned short* gB  = cenB + (size_t)(cbase + brow)       * ND + scol;
    unsigned short* lA0 = &As[(w * 32)      * 32];
    unsigned short* lA1 = &As[(w * 32 + 16) * 32];
    unsigned short* lB  = &Bs[(w * 16)      * 32];

    f32x4 acc[4][2] = {};   // 4 row-frags x 2 col-frags of 16x16

    for (int kb = 0; kb < ND; kb += 32) {
        __syncthreads();                       // prev iter's ds_reads done
        GLOAD_LDS16(gA0 + kb, lA0);
        GLOAD_LDS16(gA1 + kb, lA1);
        GLOAD_LDS16(gB  + kb, lB);
        __syncthreads();                       // drains vmcnt -> tile visible

        bf16x8 a[4], b[2];
        #pragma unroll
        for (int i = 0; i < 4; ++i)
            a[i] = *(const bf16x8*)&As[(wm * 64 + i * 16 + ln) * 32 + qd * 8];
        #pragma unroll
        for (int j = 0; j < 2; ++j)
            b[j] = *(const bf16x8*)&Bs[(wn * 32 + j * 16 + ln) * 32 + qd * 8];
        #pragma unroll
        for (int i = 0; i < 4; ++i)
            #pragma unroll
            for (int j = 0; j < 2; ++j)
                acc[i][j] = __builtin_amdgcn_mfma_f32_16x16x32_bf16(a[i], b[j], acc[i][j], 0, 0, 0);
    }

    // Epilogue. C/D layout: col = lane&15, row = (lane>>4)*4 + reg.
    #pragma unroll
    for (int i = 0; i < 4; ++i) {
        #pragma unroll
        for (int r = 0; r < 4; ++r) {
            const int rlocal = wm * 64 + i * 16 + qd * 4 + r;
            const int grow   = rbase + rlocal;
            const int tr     = tgtL[rlocal];
            float m = BIGF;
            #pragma unroll
            for (int j = 0; j < 2; ++j) {
                const int clocal = wn * 32 + j * 16 + ln;
                const float val = csqL[clocal] - 2.0f * acc[i][j][r];
                if (cbase + clocal == tr) {
                    apval[grow] = val;                 // exactly one writer per row
                } else {
                    m = fminf(m, val);
                }
            }
            #pragma unroll
            for (int off = 1; off < 16; off <<= 1)     // min over 16 cols in-wave
                m = fminf(m, __shfl_xor(m, off));
            if (ln == 0) atomicMin(&ldsmin[rlocal], fkey(m));
        }
    }
    __syncthreads();
    if (tid < 128) {
        unsigned v = ldsmin[tid];
        if (v != 0xFFFFFFFFu) atomicMin(&negmin[rbase + tid], v);
    }
}

// -------------------------------------------------------------------------
// k3: finalize + reduce, single block (reads only 96 KB of per-row scalars).
// -------------------------------------------------------------------------
__global__ __launch_bounds__(1024) void k3_final(
    const float* __restrict__ rsq, const unsigned* __restrict__ negmin,
    const float* __restrict__ apval, float* __restrict__ out)
{
    __shared__ float sl[1024];
    __shared__ float sp[1024];
    const int tid = threadIdx.x;
    float a = 0.0f, p = 0.0f;
    for (int r = tid; r < NB; r += 1024) {
        float s  = rsq[r];
        float an = sqrtf(fmaxf(s + finv(negmin[r]), 1e-12f));
        float ap = sqrtf(fmaxf(s + apval[r], 1e-12f));
        a += fmaxf(0.0f, ap - an + MARGIN_F);
        p += (an > ap) ? 1.0f : 0.0f;
    }
    sl[tid] = a; sp[tid] = p;
    __syncthreads();
    #pragma unroll
    for (int s = 512; s > 0; s >>= 1) {
        if (tid < s) { sl[tid] += sl[tid + s]; sp[tid] += sp[tid + s]; }
        __syncthreads();
    }
    if (tid == 0) {
        out[0] = sl[0] / (float)NB;
        out[1] = sp[0] / (float)NB;
    }
}

extern "C" void kernel_launch(void* const* d_in, const int* in_sizes, int n_in,
                              void* d_out, int out_size, void* d_ws, size_t ws_size,
                              hipStream_t stream) {
    const float* inputs  = (const float*)d_in[0];
    const int*   targets = (const int*)d_in[1];
    const float* centers = (const float*)d_in[2];
    float* out = (float*)d_out;

    // ws layout (bytes):
    char* wp = (char*)d_ws;
    unsigned short* inB    = (unsigned short*)(wp);             // 8192*512*2 = 8388608
    unsigned short* cenB   = (unsigned short*)(wp + 8388608);   // 512*512*2  = 524288
    float*          rsq    = (float*)(wp + 8912896);            // 8192*4
    float*          csqv   = (float*)(wp + 8945664);            // 512*4
    unsigned*       counts = (unsigned*)(wp + 8947712);         // 512*4
    unsigned*       negmin = (unsigned*)(wp + 8949760);         // 8192*4
    float*          apval  = (float*)(wp + 8982528);            // 8192*4

    k0_prep<<<2177, 256, 0, stream>>>(inputs, targets, centers,
                                      inB, cenB, rsq, csqv, counts, negmin);
    k2_mfma<<<512, 256, 0, stream>>>(inB, cenB, targets, counts, csqv,
                                     negmin, apval);
    k3_final<<<1, 1024, 0, stream>>>(rsq, negmin, apval, out);
}